// Round 1
// baseline (4595.177 us; speedup 1.0000x reference)
//
#include <hip/hip_runtime.h>
#include <hip/hip_bf16.h>
#include <math.h>

// Problem constants
#define B_ 4
#define T_ 2048
#define E_ 768
#define H_ 6
#define D_ 128
#define M_ (B_*T_)   // 8192 rows
#define GK E_        // inner dim of all GEMMs = 768

// ---------------------------------------------------------------------------
// K0: RoPE tables  cos/sin[t][j], j in [0,64)
// inv_freq[j] = 10000^(-2j/128) = 10000^(-j/64)
// ---------------------------------------------------------------------------
__global__ void k_rope_tables(float* __restrict__ cosT, float* __restrict__ sinT) {
  int t = blockIdx.x;
  int j = threadIdx.x; // 0..63
  float inv = powf(10000.0f, -(float)j * (1.0f/64.0f));
  float f = (float)t * inv;
  cosT[t*64 + j] = cosf(f);
  sinT[t*64 + j] = sinf(f);
}

// ---------------------------------------------------------------------------
// K1/K4: C[m][n] = sum_k A[m][k] * W[n][k]   (A row-stride 768, W row-stride 768)
// C row-stride ldc; C pointer may be pre-offset for column base.
// grid (M_/128, Nw/64), block 256. LDS tiles stored k-major for b128 reads.
// ---------------------------------------------------------------------------
__global__ __launch_bounds__(256) void k_gemm_xwt(
    const float* __restrict__ A, const float* __restrict__ W,
    float* __restrict__ C, int ldc) {
  __shared__ float As[16][128];
  __shared__ float Bs[16][64];
  const int tid = threadIdx.x;
  const int m0 = blockIdx.x * 128;
  const int n0 = blockIdx.y * 64;
  const int ty = tid >> 3;   // 0..31 -> rows ty*4 .. ty*4+3
  const int tx = tid & 7;    // 0..7  -> cols tx*8 .. tx*8+7
  float acc[4][8];
  #pragma unroll
  for (int i = 0; i < 4; ++i)
    #pragma unroll
    for (int j = 0; j < 8; ++j) acc[i][j] = 0.0f;

  for (int k0 = 0; k0 < GK; k0 += 16) {
    // stage A tile 128x16 (512 float4 slots)
    #pragma unroll
    for (int it = 0; it < 2; ++it) {
      int slot = tid + it*256;
      int row = slot >> 2;
      int kq  = slot & 3;
      float4 av = *reinterpret_cast<const float4*>(&A[(size_t)(m0+row)*GK + k0 + kq*4]);
      As[kq*4+0][row] = av.x;
      As[kq*4+1][row] = av.y;
      As[kq*4+2][row] = av.z;
      As[kq*4+3][row] = av.w;
    }
    // stage W tile 64x16 (256 float4 slots)
    {
      int row = tid >> 2;
      int kq  = tid & 3;
      float4 bv = *reinterpret_cast<const float4*>(&W[(size_t)(n0+row)*GK + k0 + kq*4]);
      Bs[kq*4+0][row] = bv.x;
      Bs[kq*4+1][row] = bv.y;
      Bs[kq*4+2][row] = bv.z;
      Bs[kq*4+3][row] = bv.w;
    }
    __syncthreads();
    #pragma unroll
    for (int kk = 0; kk < 16; ++kk) {
      float a[4], b[8];
      *reinterpret_cast<float4*>(a)   = *reinterpret_cast<const float4*>(&As[kk][ty*4]);
      *reinterpret_cast<float4*>(b)   = *reinterpret_cast<const float4*>(&Bs[kk][tx*8]);
      *reinterpret_cast<float4*>(b+4) = *reinterpret_cast<const float4*>(&Bs[kk][tx*8+4]);
      #pragma unroll
      for (int i = 0; i < 4; ++i)
        #pragma unroll
        for (int j = 0; j < 8; ++j)
          acc[i][j] = fmaf(a[i], b[j], acc[i][j]);
    }
    __syncthreads();
  }
  #pragma unroll
  for (int i = 0; i < 4; ++i) {
    float4 o0 = make_float4(acc[i][0], acc[i][1], acc[i][2], acc[i][3]);
    float4 o1 = make_float4(acc[i][4], acc[i][5], acc[i][6], acc[i][7]);
    size_t base = (size_t)(m0 + ty*4 + i)*ldc + n0 + tx*8;
    *reinterpret_cast<float4*>(&C[base])     = o0;
    *reinterpret_cast<float4*>(&C[base + 4]) = o1;
  }
}

// ---------------------------------------------------------------------------
// K2: v-mix + rms-norm + rope
// grid (8192, 8), block 128. row 0..5 = q heads, 6 = k, 7 = v (mix only)
// qkv layout: [bt][1024] with cols 0..767 q, 768..895 k, 896..1023 v
// ---------------------------------------------------------------------------
__global__ __launch_bounds__(128) void k_vmix_norm_rope(
    const float* __restrict__ qkv, const float* __restrict__ v1,
    const float* __restrict__ lambp,
    const float* __restrict__ cosT, const float* __restrict__ sinT,
    float* __restrict__ qn, float* __restrict__ kn, float* __restrict__ vn) {
  const int bt  = blockIdx.x;          // 0..8191
  const int row = blockIdx.y;          // 0..7
  const int d   = threadIdx.x;         // 0..127
  const int t   = bt & (T_-1);
  float val = qkv[(size_t)bt*1024 + row*128 + d];
  if (row == 7) {
    float lamb = *lambp;
    vn[(size_t)bt*128 + d] = (1.0f - lamb)*val + lamb*v1[(size_t)bt*128 + d];
    return;
  }
  __shared__ float red[2];
  __shared__ float nbuf[128];
  float ss = val*val;
  #pragma unroll
  for (int off = 32; off > 0; off >>= 1) ss += __shfl_xor(ss, off);
  if ((threadIdx.x & 63) == 0) red[threadIdx.x >> 6] = ss;
  __syncthreads();
  float sum = red[0] + red[1];
  float r = rsqrtf(sum * (1.0f/128.0f) + 1e-6f);
  nbuf[d] = val * r;
  __syncthreads();
  int j = d & 63;
  float c = cosT[t*64 + j];
  float s = sinT[t*64 + j];
  float o = (d < 64) ? (nbuf[d]*c + nbuf[d+64]*s)
                     : (-nbuf[d-64]*s + nbuf[d]*c);
  if (row < 6) qn[((size_t)bt*H_ + row)*D_ + d] = o;
  else         kn[(size_t)bt*D_ + d] = o;
}

// ---------------------------------------------------------------------------
// K3: causal attention, online softmax. One wave handles TQ=4 q-rows of one
// (b,h). Lane owns d-pair (2*lane, 2*lane+1). Fuses sigmoid gate.
// ---------------------------------------------------------------------------
#define TQ 4
__global__ __launch_bounds__(64) void k_attn(
    const float* __restrict__ qn, const float* __restrict__ kn,
    const float* __restrict__ vn, const float* __restrict__ x,
    const float* __restrict__ Wg, float* __restrict__ y) {
  const int lane = threadIdx.x;
  const int NT = T_ / TQ; // 512
  int bid = blockIdx.x;
  const int tq = bid % NT;
  const int h  = (bid / NT) % H_;
  const int b  = bid / (NT * H_);
  const int t0 = tq * TQ;

  float2 qr[TQ];
  float m[TQ], l[TQ];
  float2 acc[TQ];
  #pragma unroll
  for (int i = 0; i < TQ; ++i) {
    qr[i] = *reinterpret_cast<const float2*>(
        &qn[(((size_t)b*T_ + t0 + i)*H_ + h)*D_ + 2*lane]);
    m[i] = -3.0e38f; l[i] = 0.0f; acc[i] = make_float2(0.0f, 0.0f);
  }
  const float* kb = kn + (size_t)b*T_*D_;
  const float* vb = vn + (size_t)b*T_*D_;

  for (int s = 0; s <= t0 + TQ - 1; ++s) {
    float2 kv = *reinterpret_cast<const float2*>(&kb[(size_t)s*D_ + 2*lane]);
    float2 vv = *reinterpret_cast<const float2*>(&vb[(size_t)s*D_ + 2*lane]);
    float p0 = qr[0].x*kv.x + qr[0].y*kv.y;
    float p1 = qr[1].x*kv.x + qr[1].y*kv.y;
    float p2 = qr[2].x*kv.x + qr[2].y*kv.y;
    float p3 = qr[3].x*kv.x + qr[3].y*kv.y;
    #pragma unroll
    for (int off = 32; off > 0; off >>= 1) {
      p0 += __shfl_xor(p0, off);
      p1 += __shfl_xor(p1, off);
      p2 += __shfl_xor(p2, off);
      p3 += __shfl_xor(p3, off);
    }
    float ps[TQ] = {p0, p1, p2, p3};
    #pragma unroll
    for (int i = 0; i < TQ; ++i) {
      if (s <= t0 + i) {             // wave-uniform branch
        float sc = ps[i] * 0.1f;
        float mn = fmaxf(m[i], sc);
        float e0 = __expf(m[i] - mn);
        float p  = __expf(sc - mn);
        l[i] = l[i]*e0 + p;
        acc[i].x = acc[i].x*e0 + p*vv.x;
        acc[i].y = acc[i].y*e0 + p*vv.y;
        m[i] = mn;
      }
    }
  }
  #pragma unroll
  for (int i = 0; i < TQ; ++i) {
    float dotg = 0.0f;
    #pragma unroll
    for (int jj = 0; jj < 12; ++jj)
      dotg += x[((size_t)b*T_ + t0 + i)*E_ + jj] * Wg[h*12 + jj];
    float g = 1.0f / (1.0f + __expf(-dotg));
    float inv_l = g / l[i];
    float2 o = make_float2(acc[i].x*inv_l, acc[i].y*inv_l);
    *reinterpret_cast<float2*>(
        &y[(((size_t)b*T_ + t0 + i)*H_ + h)*D_ + 2*lane]) = o;
  }
}

// ---------------------------------------------------------------------------
extern "C" void kernel_launch(void* const* d_in, const int* in_sizes, int n_in,
                              void* d_out, int out_size, void* d_ws, size_t ws_size,
                              hipStream_t stream) {
  const float* x    = (const float*)d_in[0];
  const float* v1   = (const float*)d_in[1];
  const float* Wq   = (const float*)d_in[2];
  const float* Wk   = (const float*)d_in[3];
  const float* Wv   = (const float*)d_in[4];
  const float* lamb = (const float*)d_in[5];
  const float* Wo   = (const float*)d_in[6];
  const float* Wg   = (const float*)d_in[7];
  float* out = (float*)d_out;
  float* ws  = (float*)d_ws;

  // workspace layout (floats)
  float* qkv  = ws;                       // 8192*1024 = 8388608 (dead after K2)
  float* y    = ws;                       // alias: y 8192*768 written by K3
  float* qn   = ws + 8388608;             // 8192*768 = 6291456
  float* kn   = qn + 6291456;             // 8192*128 = 1048576
  float* vn   = kn + 1048576;             // 1048576
  float* cosT = vn + 1048576;             // 2048*64 = 131072
  float* sinT = cosT + 131072;            // 131072
  // total = 17039360 floats = 68.2 MB

  k_rope_tables<<<T_, 64, 0, stream>>>(cosT, sinT);

  k_gemm_xwt<<<dim3(M_/128, 12), 256, 0, stream>>>(x, Wq, qkv,       1024);
  k_gemm_xwt<<<dim3(M_/128,  2), 256, 0, stream>>>(x, Wk, qkv + 768, 1024);
  k_gemm_xwt<<<dim3(M_/128,  2), 256, 0, stream>>>(x, Wv, qkv + 896, 1024);

  k_vmix_norm_rope<<<dim3(M_, 8), 128, 0, stream>>>(qkv, v1, lamb, cosT, sinT,
                                                    qn, kn, vn);

  k_attn<<<B_*H_*(T_/TQ), 64, 0, stream>>>(qn, kn, vn, x, Wg, y);

  k_gemm_xwt<<<dim3(M_/128, 12), 256, 0, stream>>>(y, Wo, out, E_);

  // second output: v1 passthrough
  hipMemcpyAsync(out + (size_t)M_*E_, v1, (size_t)M_*D_*sizeof(float),
                 hipMemcpyDeviceToDevice, stream);
}

// Round 3
// 706.165 us; speedup vs baseline: 6.5072x; 6.5072x over previous
//
#include <hip/hip_runtime.h>
#include <hip/hip_bf16.h>
#include <math.h>

// Problem constants
#define B_ 4
#define T_ 2048
#define E_ 768
#define H_ 6
#define D_ 128
#define M_ (B_*T_)   // 8192 rows
#define GK E_        // inner dim of all GEMMs = 768

typedef __attribute__((ext_vector_type(8))) short short8;
typedef __attribute__((ext_vector_type(4))) float f32x4;
typedef unsigned short u16;

__device__ inline u16 f2b(float x) {
  union { float f; unsigned u; } c; c.f = x;
  unsigned r = (c.u + 0x7fff + ((c.u >> 16) & 1)) >> 16;  // RNE
  return (u16)r;
}

// ---------------------------------------------------------------------------
// K0: RoPE tables
// ---------------------------------------------------------------------------
__global__ void k_rope_tables(float* __restrict__ cosT, float* __restrict__ sinT) {
  int t = blockIdx.x;
  int j = threadIdx.x; // 0..63
  float inv = powf(10000.0f, -(float)j * (1.0f/64.0f));
  float f = (float)t * inv;
  cosT[t*64 + j] = cosf(f);
  sinT[t*64 + j] = sinf(f);
}

// ---------------------------------------------------------------------------
// K1/K4: f32 GEMM C[m][n] = sum_k A[m][k] * W[n][k]
// ---------------------------------------------------------------------------
__global__ __launch_bounds__(256) void k_gemm_xwt(
    const float* __restrict__ A, const float* __restrict__ W,
    float* __restrict__ C, int ldc) {
  __shared__ float As[16][128];
  __shared__ float Bs[16][64];
  const int tid = threadIdx.x;
  const int m0 = blockIdx.x * 128;
  const int n0 = blockIdx.y * 64;
  const int ty = tid >> 3;
  const int tx = tid & 7;
  float acc[4][8];
  #pragma unroll
  for (int i = 0; i < 4; ++i)
    #pragma unroll
    for (int j = 0; j < 8; ++j) acc[i][j] = 0.0f;

  for (int k0 = 0; k0 < GK; k0 += 16) {
    #pragma unroll
    for (int it = 0; it < 2; ++it) {
      int slot = tid + it*256;
      int row = slot >> 2;
      int kq  = slot & 3;
      float4 av = *reinterpret_cast<const float4*>(&A[(size_t)(m0+row)*GK + k0 + kq*4]);
      As[kq*4+0][row] = av.x;
      As[kq*4+1][row] = av.y;
      As[kq*4+2][row] = av.z;
      As[kq*4+3][row] = av.w;
    }
    {
      int row = tid >> 2;
      int kq  = tid & 3;
      float4 bv = *reinterpret_cast<const float4*>(&W[(size_t)(n0+row)*GK + k0 + kq*4]);
      Bs[kq*4+0][row] = bv.x;
      Bs[kq*4+1][row] = bv.y;
      Bs[kq*4+2][row] = bv.z;
      Bs[kq*4+3][row] = bv.w;
    }
    __syncthreads();
    #pragma unroll
    for (int kk = 0; kk < 16; ++kk) {
      float a[4], bb[8];
      *reinterpret_cast<float4*>(a)    = *reinterpret_cast<const float4*>(&As[kk][ty*4]);
      *reinterpret_cast<float4*>(bb)   = *reinterpret_cast<const float4*>(&Bs[kk][tx*8]);
      *reinterpret_cast<float4*>(bb+4) = *reinterpret_cast<const float4*>(&Bs[kk][tx*8+4]);
      #pragma unroll
      for (int i = 0; i < 4; ++i)
        #pragma unroll
        for (int j = 0; j < 8; ++j)
          acc[i][j] = fmaf(a[i], bb[j], acc[i][j]);
    }
    __syncthreads();
  }
  #pragma unroll
  for (int i = 0; i < 4; ++i) {
    float4 o0 = make_float4(acc[i][0], acc[i][1], acc[i][2], acc[i][3]);
    float4 o1 = make_float4(acc[i][4], acc[i][5], acc[i][6], acc[i][7]);
    size_t base = (size_t)(m0 + ty*4 + i)*ldc + n0 + tx*8;
    *reinterpret_cast<float4*>(&C[base])     = o0;
    *reinterpret_cast<float4*>(&C[base + 4]) = o1;
  }
}

// ---------------------------------------------------------------------------
// K2: v-mix + rms-norm + rope. Outputs bf16:
//   qn [b][h][t][d]   (head-major so attention reads are contiguous per head)
//   kn [b][t][d]
//   vn [b][t][d]
// ---------------------------------------------------------------------------
__global__ __launch_bounds__(128) void k_vmix_norm_rope(
    const float* __restrict__ qkv, const float* __restrict__ v1,
    const float* __restrict__ lambp,
    const float* __restrict__ cosT, const float* __restrict__ sinT,
    u16* __restrict__ qn, u16* __restrict__ kn, u16* __restrict__ vn) {
  const int bt  = blockIdx.x;
  const int row = blockIdx.y;          // 0..5 q heads, 6 = k, 7 = v
  const int d   = threadIdx.x;
  const int t   = bt & (T_-1);
  const int b   = bt >> 11;
  float val = qkv[(size_t)bt*1024 + row*128 + d];
  if (row == 7) {
    float lamb = *lambp;
    float mix = (1.0f - lamb)*val + lamb*v1[(size_t)bt*128 + d];
    vn[(size_t)bt*128 + d] = f2b(mix);
    return;
  }
  __shared__ float red[2];
  __shared__ float nbuf[128];
  float ss = val*val;
  #pragma unroll
  for (int off = 32; off > 0; off >>= 1) ss += __shfl_xor(ss, off);
  if ((threadIdx.x & 63) == 0) red[threadIdx.x >> 6] = ss;
  __syncthreads();
  float sum = red[0] + red[1];
  float r = rsqrtf(sum * (1.0f/128.0f) + 1e-6f);
  nbuf[d] = val * r;
  __syncthreads();
  int j = d & 63;
  float c = cosT[t*64 + j];
  float s = sinT[t*64 + j];
  float o = (d < 64) ? (nbuf[d]*c + nbuf[d+64]*s)
                     : (-nbuf[d-64]*s + nbuf[d]*c);
  if (row < 6) qn[((size_t)(b*H_ + row)*T_ + t)*D_ + d] = f2b(o);
  else         kn[(size_t)bt*D_ + d] = f2b(o);
}

// ---------------------------------------------------------------------------
// K3: MFMA flash attention (MQA). Block = 4 waves, 128 q-rows of one (b,h).
// Wave w owns rows [t0b + 32w, t0b + 32w + 32). KV tiles of 32 staged in LDS:
//   Kt: [32][128] bf16 row-major, XOR-swizzled (byte ^= (row&7)<<4)
//   Vt: [128][40] bf16 transposed (pad 40 kills bank conflicts)
//   Pl: per-wave [32][32] bf16 swizzled (C-layout write -> A-layout read)
// ---------------------------------------------------------------------------
#define KVB 32
__global__ __launch_bounds__(256) void k_attn_mfma(
    const u16* __restrict__ qn, const u16* __restrict__ kn,
    const u16* __restrict__ vn, const float* __restrict__ x,
    const float* __restrict__ Wg, float* __restrict__ y) {
  __shared__ __align__(16) u16 Kt[32*128];
  __shared__ __align__(16) u16 Vt[128*40];
  __shared__ __align__(16) u16 Pl[4*1024];

  const int tid  = threadIdx.x;
  const int lane = tid & 63;
  const int wv   = tid >> 6;
  const int lo   = lane & 15;
  const int hi   = lane >> 4;

  const int bid = blockIdx.x;
  const int qt  = 15 - (bid & 15);          // big q-tiles first
  const int h   = (bid >> 4) % H_;
  const int b   = bid / (16 * H_);
  const int t0b = qt * 128;
  const int t0w = t0b + wv * 32;

  // Q fragments: qa[qi][ks], A-layout (row = lane&15, k = (lane>>4)*8+j)
  short8 qa[2][4];
  const u16* qb = qn + ((size_t)(b*H_ + h)*T_ + t0w)*D_;
  #pragma unroll
  for (int qi = 0; qi < 2; ++qi)
    #pragma unroll
    for (int ks = 0; ks < 4; ++ks)
      qa[qi][ks] = *(const short8*)(qb + (size_t)(qi*16 + lo)*D_ + ks*32 + hi*8);

  f32x4 acc[2][8];
  float mrow[2][4], lrow[2][4];
  #pragma unroll
  for (int qi = 0; qi < 2; ++qi) {
    #pragma unroll
    for (int dj = 0; dj < 8; ++dj) {
      acc[qi][dj][0]=0.f; acc[qi][dj][1]=0.f; acc[qi][dj][2]=0.f; acc[qi][dj][3]=0.f;
    }
    #pragma unroll
    for (int r = 0; r < 4; ++r) { mrow[qi][r] = -1e30f; lrow[qi][r] = 0.f; }
  }

  const u16* kg = kn + (size_t)b*T_*D_;
  const u16* vg = vn + (size_t)b*T_*D_;

  const int kvend = t0b + 128;
  for (int kv0 = 0; kv0 < kvend; kv0 += KVB) {
    __syncthreads();
    // stage K tile (swizzled row-major): thread -> s = tid>>3, d0 = (tid&7)*16
    {
      int s = tid >> 3, d0 = (tid & 7) * 16;
      const u16* src = kg + (size_t)(kv0 + s)*D_ + d0;
      short8 a = *(const short8*)(src);
      short8 c = *(const short8*)(src + 8);
      int ba = (s*256 + d0*2) ^ ((s & 7) << 4);
      *(short8*)((char*)Kt + ba)        = a;   // d0*2 is mult of 32 -> ^16 safe
      *(short8*)((char*)Kt + (ba ^ 16)) = c;
    }
    // stage V transposed: thread -> s = tid&31, d0 = (tid>>5)*16
    {
      int s = tid & 31, d0 = (tid >> 5) * 16;
      const u16* src = vg + (size_t)(kv0 + s)*D_ + d0;
      short8 a = *(const short8*)(src);
      short8 c = *(const short8*)(src + 8);
      #pragma unroll
      for (int j = 0; j < 8; ++j) {
        Vt[(d0 + j)*40 + s]     = (u16)a[j];
        Vt[(d0 + 8 + j)*40 + s] = (u16)c[j];
      }
    }
    __syncthreads();

    if (kv0 >= t0w + 32) continue;   // tile fully above diagonal for this wave

    // ---- QK^T: sc[qi][kj] 16x16 tiles, K-dim = 128 via 4 slices ----
    f32x4 sc[2][2];
    #pragma unroll
    for (int qi = 0; qi < 2; ++qi)
      #pragma unroll
      for (int kj = 0; kj < 2; ++kj) {
        sc[qi][kj][0]=0.f; sc[qi][kj][1]=0.f; sc[qi][kj][2]=0.f; sc[qi][kj][3]=0.f;
      }
    #pragma unroll
    for (int kj = 0; kj < 2; ++kj) {
      short8 kb[4];
      #pragma unroll
      for (int ks = 0; ks < 4; ++ks) {
        int row = kj*16 + lo;
        int ba = (row*256 + ks*64 + hi*16) ^ ((row & 7) << 4);
        kb[ks] = *(const short8*)((char*)Kt + ba);
      }
      #pragma unroll
      for (int qi = 0; qi < 2; ++qi)
        #pragma unroll
        for (int ks = 0; ks < 4; ++ks)
          sc[qi][kj] = __builtin_amdgcn_mfma_f32_16x16x32_bf16(
              qa[qi][ks], kb[ks], sc[qi][kj], 0, 0, 0);
    }

    // ---- online softmax in C layout (row = hi*4+r, col = lo) ----
    const bool needmask = (kv0 + KVB - 1 > t0w);
    float p[2][2][4];
    #pragma unroll
    for (int qi = 0; qi < 2; ++qi) {
      #pragma unroll
      for (int r = 0; r < 4; ++r) {
        float s0 = sc[qi][0][r]*0.1f, s1 = sc[qi][1][r]*0.1f;
        if (needmask) {
          int row = t0w + qi*16 + hi*4 + r;
          s0 = (kv0 + lo      <= row) ? s0 : -1e30f;
          s1 = (kv0 + 16 + lo <= row) ? s1 : -1e30f;
        }
        float mx = fmaxf(s0, s1);
        mx = fmaxf(mx, __shfl_xor(mx, 1));
        mx = fmaxf(mx, __shfl_xor(mx, 2));
        mx = fmaxf(mx, __shfl_xor(mx, 4));
        mx = fmaxf(mx, __shfl_xor(mx, 8));
        float mo = mrow[qi][r];
        float mn = fmaxf(mo, mx);
        float scale = __expf(mo - mn);
        float p0 = __expf(s0 - mn);
        float p1 = __expf(s1 - mn);
        mrow[qi][r] = mn;
        lrow[qi][r] = lrow[qi][r]*scale + p0 + p1;  // per-lane partial
        p[qi][0][r] = p0; p[qi][1][r] = p1;
        #pragma unroll
        for (int dj = 0; dj < 8; ++dj) acc[qi][dj][r] *= scale;
      }
    }

    // ---- P: C-layout regs -> wave-private swizzled LDS -> A-layout frags ----
    #pragma unroll
    for (int qi = 0; qi < 2; ++qi)
      #pragma unroll
      for (int kj = 0; kj < 2; ++kj)
        #pragma unroll
        for (int r = 0; r < 4; ++r) {
          int row = qi*16 + hi*4 + r;
          int col = kj*16 + lo;
          int ba = (row*64 + col*2) ^ ((row & 7) << 4);
          *(u16*)((char*)Pl + wv*2048 + ba) = f2b(p[qi][kj][r]);
        }
    short8 pa[2];
    #pragma unroll
    for (int qi = 0; qi < 2; ++qi) {
      int row = qi*16 + lo;
      int ba = (row*64 + hi*16) ^ ((row & 7) << 4);
      pa[qi] = *(const short8*)((char*)Pl + wv*2048 + ba);
    }
    // ---- PV: acc[qi][dj] += P[32s] x V[s][d] ----
    #pragma unroll
    for (int dj = 0; dj < 8; ++dj) {
      short8 vb = *(const short8*)(&Vt[(dj*16 + lo)*40 + hi*8]);
      #pragma unroll
      for (int qi = 0; qi < 2; ++qi)
        acc[qi][dj] = __builtin_amdgcn_mfma_f32_16x16x32_bf16(
            pa[qi], vb, acc[qi][dj], 0, 0, 0);
    }
  }

  // ---- epilogue: reduce l, gate, write y (f32, [bt][768], col = h*128+d) ----
  #pragma unroll
  for (int qi = 0; qi < 2; ++qi)
    #pragma unroll
    for (int r = 0; r < 4; ++r) {
      float lv = lrow[qi][r];
      lv += __shfl_xor(lv, 1);
      lv += __shfl_xor(lv, 2);
      lv += __shfl_xor(lv, 4);
      lv += __shfl_xor(lv, 8);
      lrow[qi][r] = lv;
    }
  #pragma unroll
  for (int qi = 0; qi < 2; ++qi)
    #pragma unroll
    for (int r = 0; r < 4; ++r) {
      int trow = t0w + qi*16 + hi*4 + r;
      size_t bt = (size_t)b*T_ + trow;
      float dotg = 0.f;
      #pragma unroll
      for (int jj = 0; jj < 12; ++jj)
        dotg += x[bt*E_ + jj]*Wg[h*12 + jj];
      float g = 1.f/(1.f + __expf(-dotg));
      float coef = g / lrow[qi][r];
      #pragma unroll
      for (int dj = 0; dj < 8; ++dj)
        y[bt*E_ + h*D_ + dj*16 + lo] = acc[qi][dj][r]*coef;
    }
}

// ---------------------------------------------------------------------------
extern "C" void kernel_launch(void* const* d_in, const int* in_sizes, int n_in,
                              void* d_out, int out_size, void* d_ws, size_t ws_size,
                              hipStream_t stream) {
  const float* x    = (const float*)d_in[0];
  const float* v1   = (const float*)d_in[1];
  const float* Wq   = (const float*)d_in[2];
  const float* Wk   = (const float*)d_in[3];
  const float* Wv   = (const float*)d_in[4];
  const float* lamb = (const float*)d_in[5];
  const float* Wo   = (const float*)d_in[6];
  const float* Wg   = (const float*)d_in[7];
  float* out = (float*)d_out;
  float* ws  = (float*)d_ws;

  // workspace layout (float units)
  float* qkv  = ws;                        // 8192*1024 f32 (dead after K2)
  float* y    = ws;                        // alias: attention output f32
  u16*   qn   = (u16*)(ws + 8388608);      // 8192*768 bf16
  u16*   kn   = qn + (size_t)M_*E_;        // 8192*128 bf16
  u16*   vn   = kn + (size_t)M_*D_;        // 8192*128 bf16
  float* cosT = (float*)(vn + (size_t)M_*D_);
  float* sinT = cosT + 131072;

  k_rope_tables<<<T_, 64, 0, stream>>>(cosT, sinT);

  k_gemm_xwt<<<dim3(M_/128, 12), 256, 0, stream>>>(x, Wq, qkv,       1024);
  k_gemm_xwt<<<dim3(M_/128,  2), 256, 0, stream>>>(x, Wk, qkv + 768, 1024);
  k_gemm_xwt<<<dim3(M_/128,  2), 256, 0, stream>>>(x, Wv, qkv + 896, 1024);

  k_vmix_norm_rope<<<dim3(M_, 8), 128, 0, stream>>>(qkv, v1, lamb, cosT, sinT,
                                                    qn, kn, vn);

  k_attn_mfma<<<B_*H_*(T_/128), 256, 0, stream>>>(qn, kn, vn, x, Wg, y);

  k_gemm_xwt<<<dim3(M_/128, 12), 256, 0, stream>>>(y, Wo, out, E_);

  hipMemcpyAsync(out + (size_t)M_*E_, v1, (size_t)M_*D_*sizeof(float),
                 hipMemcpyDeviceToDevice, stream);
}

// Round 4
// 387.970 us; speedup vs baseline: 11.8441x; 1.8202x over previous
//
#include <hip/hip_runtime.h>
#include <hip/hip_bf16.h>
#include <math.h>

// Problem constants
#define B_ 4
#define T_ 2048
#define E_ 768
#define H_ 6
#define D_ 128
#define M_ (B_*T_)   // 8192 rows

typedef __attribute__((ext_vector_type(8))) short short8;
typedef __attribute__((ext_vector_type(4))) float f32x4;
typedef unsigned short u16;

__device__ inline u16 f2b(float x) {
  union { float f; unsigned u; } c; c.f = x;
  unsigned r = (c.u + 0x7fff + ((c.u >> 16) & 1)) >> 16;  // RNE
  return (u16)r;
}
__device__ inline float b2f(u16 x) {
  union { unsigned u; float f; } c; c.u = ((unsigned)x) << 16;
  return c.f;
}

// ---------------------------------------------------------------------------
// K0: RoPE tables
// ---------------------------------------------------------------------------
__global__ void k_rope_tables(float* __restrict__ cosT, float* __restrict__ sinT) {
  int t = blockIdx.x;
  int j = threadIdx.x; // 0..63
  float inv = powf(10000.0f, -(float)j * (1.0f/64.0f));
  float f = (float)t * inv;
  cosT[t*64 + j] = cosf(f);
  sinT[t*64 + j] = sinf(f);
}

// ---------------------------------------------------------------------------
// K0b: f32 -> bf16 conversion (n multiple of 4)
// ---------------------------------------------------------------------------
__global__ __launch_bounds__(256) void k_f2b(const float* __restrict__ in,
                                             u16* __restrict__ outp, int n) {
  int i = (blockIdx.x*256 + threadIdx.x)*4;
  if (i >= n) return;
  float4 v = *reinterpret_cast<const float4*>(in + i);
  typedef __attribute__((ext_vector_type(4))) short short4v;
  short4v o;
  o[0] = (short)f2b(v.x); o[1] = (short)f2b(v.y);
  o[2] = (short)f2b(v.z); o[3] = (short)f2b(v.w);
  *reinterpret_cast<short4v*>(outp + i) = o;
}

// ---------------------------------------------------------------------------
// K1: bf16 MFMA GEMM. C[m][n] = sum_k A[m][k]*Bw[n][k], K=768.
// Tile 128x128, BK=64, 4 waves (2x2), wave = 64x64 = 4x4 16x16x32 frags.
// LDS: As/Bs [128 rows][64 k] bf16, 128B rows, XOR-swizzled ((row&7)<<4).
// ---------------------------------------------------------------------------
__global__ __launch_bounds__(256) void k_gemm_bf16(
    const u16* __restrict__ A, const u16* __restrict__ Bw,
    void* __restrict__ Cout, int ldc, int outBf16, int ncol0) {
  __shared__ __align__(16) u16 As[128*64];
  __shared__ __align__(16) u16 Bs[128*64];
  const int tid  = threadIdx.x;
  const int lane = tid & 63;
  const int wv   = tid >> 6;
  const int lo   = lane & 15;
  const int hi   = lane >> 4;
  const int wm   = wv >> 1;
  const int wn   = wv & 1;
  const int m0   = blockIdx.x * 128;
  const int n0   = blockIdx.y * 128;

  f32x4 acc[4][4];
  #pragma unroll
  for (int i = 0; i < 4; ++i)
    #pragma unroll
    for (int j = 0; j < 4; ++j) {
      acc[i][j][0]=0.f; acc[i][j][1]=0.f; acc[i][j][2]=0.f; acc[i][j][3]=0.f;
    }

  for (int k0 = 0; k0 < E_; k0 += 64) {
    __syncthreads();   // previous-iter frag reads done before overwrite
    #pragma unroll
    for (int i = 0; i < 4; ++i) {
      int s   = i*256 + tid;     // 0..1023
      int row = s >> 3;          // 0..127
      int sl  = s & 7;           // 16B slot in 128B row
      short8 va = *reinterpret_cast<const short8*>(
          A  + (size_t)(m0+row)*E_ + k0 + sl*8);
      short8 vb = *reinterpret_cast<const short8*>(
          Bw + (size_t)(n0+row)*E_ + k0 + sl*8);
      int ba = (row*128 + sl*16) ^ ((row & 7) << 4);
      *(short8*)((char*)As + ba) = va;
      *(short8*)((char*)Bs + ba) = vb;
    }
    __syncthreads();
    #pragma unroll
    for (int ks = 0; ks < 2; ++ks) {
      short8 af[4], bf[4];
      #pragma unroll
      for (int mi = 0; mi < 4; ++mi) {
        int row = wm*64 + mi*16 + lo;
        int ba = (row*128 + ks*64 + hi*16) ^ ((row & 7) << 4);
        af[mi] = *(const short8*)((char*)As + ba);
      }
      #pragma unroll
      for (int nf = 0; nf < 4; ++nf) {
        int row = wn*64 + nf*16 + lo;
        int ba = (row*128 + ks*64 + hi*16) ^ ((row & 7) << 4);
        bf[nf] = *(const short8*)((char*)Bs + ba);
      }
      #pragma unroll
      for (int mi = 0; mi < 4; ++mi)
        #pragma unroll
        for (int nf = 0; nf < 4; ++nf)
          acc[mi][nf] = __builtin_amdgcn_mfma_f32_16x16x32_bf16(
              af[mi], bf[nf], acc[mi][nf], 0, 0, 0);
    }
  }

  // epilogue: C row = hi*4+r (within 16), col = lo
  #pragma unroll
  for (int mi = 0; mi < 4; ++mi)
    #pragma unroll
    for (int nf = 0; nf < 4; ++nf)
      #pragma unroll
      for (int r = 0; r < 4; ++r) {
        int m = m0 + wm*64 + mi*16 + hi*4 + r;
        int n = ncol0 + n0 + wn*64 + nf*16 + lo;
        float v = acc[mi][nf][r];
        if (outBf16) ((u16*)Cout)[(size_t)m*ldc + n] = f2b(v);
        else         ((float*)Cout)[(size_t)m*ldc + n] = v;
      }
}

// ---------------------------------------------------------------------------
// K2: v-mix + rms-norm + rope (reads bf16 qkv). Outputs bf16 qn/kn/vn.
// ---------------------------------------------------------------------------
__global__ __launch_bounds__(128) void k_vmix_norm_rope(
    const u16* __restrict__ qkv, const float* __restrict__ v1,
    const float* __restrict__ lambp,
    const float* __restrict__ cosT, const float* __restrict__ sinT,
    u16* __restrict__ qn, u16* __restrict__ kn, u16* __restrict__ vn) {
  const int bt  = blockIdx.x;
  const int row = blockIdx.y;          // 0..5 q heads, 6 = k, 7 = v
  const int d   = threadIdx.x;
  const int t   = bt & (T_-1);
  const int b   = bt >> 11;
  float val = b2f(qkv[(size_t)bt*1024 + row*128 + d]);
  if (row == 7) {
    float lamb = *lambp;
    float mix = (1.0f - lamb)*val + lamb*v1[(size_t)bt*128 + d];
    vn[(size_t)bt*128 + d] = f2b(mix);
    return;
  }
  __shared__ float red[2];
  __shared__ float nbuf[128];
  float ss = val*val;
  #pragma unroll
  for (int off = 32; off > 0; off >>= 1) ss += __shfl_xor(ss, off);
  if ((threadIdx.x & 63) == 0) red[threadIdx.x >> 6] = ss;
  __syncthreads();
  float sum = red[0] + red[1];
  float r = rsqrtf(sum * (1.0f/128.0f) + 1e-6f);
  nbuf[d] = val * r;
  __syncthreads();
  int j = d & 63;
  float c = cosT[t*64 + j];
  float s = sinT[t*64 + j];
  float o = (d < 64) ? (nbuf[d]*c + nbuf[d+64]*s)
                     : (-nbuf[d-64]*s + nbuf[d]*c);
  if (row < 6) qn[((size_t)(b*H_ + row)*T_ + t)*D_ + d] = f2b(o);
  else         kn[(size_t)bt*D_ + d] = f2b(o);
}

// ---------------------------------------------------------------------------
// K2b: vn [b][t][d] -> vnt [b][d][t]  (LDS-tiled transpose, 64t x 128d tiles)
// ---------------------------------------------------------------------------
__global__ __launch_bounds__(256) void k_transpose_v(
    const u16* __restrict__ vn, u16* __restrict__ vnt) {
  __shared__ u16 tile[64][136];
  const int tid = threadIdx.x;
  const int b  = blockIdx.y;
  const int t0 = blockIdx.x * 64;
  {
    int tr = tid >> 2;           // 0..63
    int dc = (tid & 3) * 32;
    const u16* src = vn + ((size_t)(b*T_ + t0 + tr))*D_ + dc;
    #pragma unroll
    for (int j = 0; j < 4; ++j) {
      short8 v = *reinterpret_cast<const short8*>(src + j*8);
      *reinterpret_cast<short8*>(&tile[tr][dc + j*8]) = v;
    }
  }
  __syncthreads();
  {
    int dr = tid >> 1;           // 0..127
    int tc = (tid & 1) * 32;
    #pragma unroll
    for (int j = 0; j < 4; ++j) {
      short8 o;
      #pragma unroll
      for (int jj = 0; jj < 8; ++jj) o[jj] = (short)tile[tc + j*8 + jj][dr];
      *reinterpret_cast<short8*>(
          vnt + ((size_t)(b*D_ + dr))*T_ + t0 + tc + j*8) = o;
    }
  }
}

// ---------------------------------------------------------------------------
// K3: MFMA flash attention (MQA). Block = 4 waves, 128 q-rows of one (b,h).
//   Kt: [32][128] bf16 row-major, XOR-swizzled
//   Vt: [128][40] bf16 = V^T tile (d-major), staged b128 from vnt
//   Pl: per-wave [32][32] bf16 swizzled
// Output yb bf16 (gate fused).
// ---------------------------------------------------------------------------
#define KVB 32
__global__ __launch_bounds__(256) void k_attn_mfma(
    const u16* __restrict__ qn, const u16* __restrict__ kn,
    const u16* __restrict__ vnt, const float* __restrict__ x,
    const float* __restrict__ Wg, u16* __restrict__ yb) {
  __shared__ __align__(16) u16 Kt[32*128];
  __shared__ __align__(16) u16 Vt[128*40];
  __shared__ __align__(16) u16 Pl[4*1024];

  const int tid  = threadIdx.x;
  const int lane = tid & 63;
  const int wv   = tid >> 6;
  const int lo   = lane & 15;
  const int hi   = lane >> 4;

  const int bid = blockIdx.x;
  const int qt  = 15 - (bid & 15);          // big q-tiles first
  const int h   = (bid >> 4) % H_;
  const int b   = bid / (16 * H_);
  const int t0b = qt * 128;
  const int t0w = t0b + wv * 32;

  short8 qa[2][4];
  const u16* qb = qn + ((size_t)(b*H_ + h)*T_ + t0w)*D_;
  #pragma unroll
  for (int qi = 0; qi < 2; ++qi)
    #pragma unroll
    for (int ks = 0; ks < 4; ++ks)
      qa[qi][ks] = *(const short8*)(qb + (size_t)(qi*16 + lo)*D_ + ks*32 + hi*8);

  f32x4 acc[2][8];
  float mrow[2][4], lrow[2][4];
  #pragma unroll
  for (int qi = 0; qi < 2; ++qi) {
    #pragma unroll
    for (int dj = 0; dj < 8; ++dj) {
      acc[qi][dj][0]=0.f; acc[qi][dj][1]=0.f; acc[qi][dj][2]=0.f; acc[qi][dj][3]=0.f;
    }
    #pragma unroll
    for (int r = 0; r < 4; ++r) { mrow[qi][r] = -1e30f; lrow[qi][r] = 0.f; }
  }

  const u16* kg  = kn  + (size_t)b*T_*D_;
  const u16* vgt = vnt + (size_t)b*D_*T_;

  const int kvend = t0b + 128;
  for (int kv0 = 0; kv0 < kvend; kv0 += KVB) {
    __syncthreads();
    // stage K tile (swizzled row-major)
    {
      int s = tid >> 3, d0 = (tid & 7) * 16;
      const u16* src = kg + (size_t)(kv0 + s)*D_ + d0;
      short8 a = *(const short8*)(src);
      short8 c = *(const short8*)(src + 8);
      int ba = (s*256 + d0*2) ^ ((s & 7) << 4);
      *(short8*)((char*)Kt + ba)        = a;
      *(short8*)((char*)Kt + (ba ^ 16)) = c;
    }
    // stage V^T tile from vnt: rows = d (128), cols = s (32), pad 40
    {
      int dr = tid >> 1;
      int sc = (tid & 1) * 16;
      const u16* src = vgt + (size_t)dr*T_ + kv0 + sc;
      short8 a = *(const short8*)(src);
      short8 c = *(const short8*)(src + 8);
      *(short8*)(&Vt[dr*40 + sc])     = a;
      *(short8*)(&Vt[dr*40 + sc + 8]) = c;
    }
    __syncthreads();

    if (kv0 >= t0w + 32) continue;

    // ---- QK^T ----
    f32x4 sc[2][2];
    #pragma unroll
    for (int qi = 0; qi < 2; ++qi)
      #pragma unroll
      for (int kj = 0; kj < 2; ++kj) {
        sc[qi][kj][0]=0.f; sc[qi][kj][1]=0.f; sc[qi][kj][2]=0.f; sc[qi][kj][3]=0.f;
      }
    #pragma unroll
    for (int kj = 0; kj < 2; ++kj) {
      short8 kb[4];
      #pragma unroll
      for (int ks = 0; ks < 4; ++ks) {
        int row = kj*16 + lo;
        int ba = (row*256 + ks*64 + hi*16) ^ ((row & 7) << 4);
        kb[ks] = *(const short8*)((char*)Kt + ba);
      }
      #pragma unroll
      for (int qi = 0; qi < 2; ++qi)
        #pragma unroll
        for (int ks = 0; ks < 4; ++ks)
          sc[qi][kj] = __builtin_amdgcn_mfma_f32_16x16x32_bf16(
              qa[qi][ks], kb[ks], sc[qi][kj], 0, 0, 0);
    }

    // ---- online softmax (C layout: row = hi*4+r, col = lo) ----
    const bool needmask = (kv0 + KVB - 1 > t0w);
    float p[2][2][4];
    #pragma unroll
    for (int qi = 0; qi < 2; ++qi) {
      #pragma unroll
      for (int r = 0; r < 4; ++r) {
        float s0 = sc[qi][0][r]*0.1f, s1 = sc[qi][1][r]*0.1f;
        if (needmask) {
          int row = t0w + qi*16 + hi*4 + r;
          s0 = (kv0 + lo      <= row) ? s0 : -1e30f;
          s1 = (kv0 + 16 + lo <= row) ? s1 : -1e30f;
        }
        float mx = fmaxf(s0, s1);
        mx = fmaxf(mx, __shfl_xor(mx, 1));
        mx = fmaxf(mx, __shfl_xor(mx, 2));
        mx = fmaxf(mx, __shfl_xor(mx, 4));
        mx = fmaxf(mx, __shfl_xor(mx, 8));
        float mo = mrow[qi][r];
        float mn = fmaxf(mo, mx);
        float scale = __expf(mo - mn);
        float p0 = __expf(s0 - mn);
        float p1 = __expf(s1 - mn);
        mrow[qi][r] = mn;
        lrow[qi][r] = lrow[qi][r]*scale + p0 + p1;
        p[qi][0][r] = p0; p[qi][1][r] = p1;
        #pragma unroll
        for (int dj = 0; dj < 8; ++dj) acc[qi][dj][r] *= scale;
      }
    }

    // ---- P via wave-private swizzled LDS ----
    #pragma unroll
    for (int qi = 0; qi < 2; ++qi)
      #pragma unroll
      for (int kj = 0; kj < 2; ++kj)
        #pragma unroll
        for (int r = 0; r < 4; ++r) {
          int row = qi*16 + hi*4 + r;
          int col = kj*16 + lo;
          int ba = (row*64 + col*2) ^ ((row & 7) << 4);
          *(u16*)((char*)Pl + wv*2048 + ba) = f2b(p[qi][kj][r]);
        }
    short8 pa[2];
    #pragma unroll
    for (int qi = 0; qi < 2; ++qi) {
      int row = qi*16 + lo;
      int ba = (row*64 + hi*16) ^ ((row & 7) << 4);
      pa[qi] = *(const short8*)((char*)Pl + wv*2048 + ba);
    }
    // ---- PV ----
    #pragma unroll
    for (int dj = 0; dj < 8; ++dj) {
      short8 vb = *(const short8*)(&Vt[(dj*16 + lo)*40 + hi*8]);
      #pragma unroll
      for (int qi = 0; qi < 2; ++qi)
        acc[qi][dj] = __builtin_amdgcn_mfma_f32_16x16x32_bf16(
            pa[qi], vb, acc[qi][dj], 0, 0, 0);
    }
  }

  // ---- epilogue ----
  #pragma unroll
  for (int qi = 0; qi < 2; ++qi)
    #pragma unroll
    for (int r = 0; r < 4; ++r) {
      float lv = lrow[qi][r];
      lv += __shfl_xor(lv, 1);
      lv += __shfl_xor(lv, 2);
      lv += __shfl_xor(lv, 4);
      lv += __shfl_xor(lv, 8);
      lrow[qi][r] = lv;
    }
  #pragma unroll
  for (int qi = 0; qi < 2; ++qi)
    #pragma unroll
    for (int r = 0; r < 4; ++r) {
      int trow = t0w + qi*16 + hi*4 + r;
      size_t bt = (size_t)b*T_ + trow;
      float dotg = 0.f;
      #pragma unroll
      for (int jj = 0; jj < 12; ++jj)
        dotg += x[bt*E_ + jj]*Wg[h*12 + jj];
      float g = 1.f/(1.f + __expf(-dotg));
      float coef = g / lrow[qi][r];
      #pragma unroll
      for (int dj = 0; dj < 8; ++dj)
        yb[bt*E_ + h*D_ + dj*16 + lo] = f2b(acc[qi][dj][r]*coef);
    }
}

// ---------------------------------------------------------------------------
extern "C" void kernel_launch(void* const* d_in, const int* in_sizes, int n_in,
                              void* d_out, int out_size, void* d_ws, size_t ws_size,
                              hipStream_t stream) {
  const float* x    = (const float*)d_in[0];
  const float* v1   = (const float*)d_in[1];
  const float* Wq   = (const float*)d_in[2];
  const float* Wk   = (const float*)d_in[3];
  const float* Wv   = (const float*)d_in[4];
  const float* lamb = (const float*)d_in[5];
  const float* Wo   = (const float*)d_in[6];
  const float* Wg   = (const float*)d_in[7];
  float* out = (float*)d_out;

  // workspace layout (u16 units for bf16 buffers)
  u16* xb   = (u16*)d_ws;
  u16* qkvb = xb   + (size_t)M_*E_;        // 8192*1024
  u16* qn   = qkvb + (size_t)M_*1024;
  u16* kn   = qn   + (size_t)M_*E_;
  u16* vn   = kn   + (size_t)M_*D_;
  u16* vnt  = vn   + (size_t)M_*D_;
  u16* yb   = vnt  + (size_t)M_*D_;
  u16* Wqb  = yb   + (size_t)M_*E_;
  u16* Wkb  = Wqb  + (size_t)E_*E_;
  u16* Wvb  = Wkb  + (size_t)D_*E_;
  u16* Wob  = Wvb  + (size_t)D_*E_;
  float* cosT = (float*)(Wob + (size_t)E_*E_);
  float* sinT = cosT + T_*64;

  k_rope_tables<<<T_, 64, 0, stream>>>(cosT, sinT);

  k_f2b<<<(M_*E_/4 + 255)/256, 256, 0, stream>>>(x,  xb,  M_*E_);
  k_f2b<<<(E_*E_/4 + 255)/256, 256, 0, stream>>>(Wq, Wqb, E_*E_);
  k_f2b<<<(D_*E_/4 + 255)/256, 256, 0, stream>>>(Wk, Wkb, D_*E_);
  k_f2b<<<(D_*E_/4 + 255)/256, 256, 0, stream>>>(Wv, Wvb, D_*E_);
  k_f2b<<<(E_*E_/4 + 255)/256, 256, 0, stream>>>(Wo, Wob, E_*E_);

  k_gemm_bf16<<<dim3(M_/128, 6), 256, 0, stream>>>(xb, Wqb, qkvb, 1024, 1, 0);
  k_gemm_bf16<<<dim3(M_/128, 1), 256, 0, stream>>>(xb, Wkb, qkvb, 1024, 1, 768);
  k_gemm_bf16<<<dim3(M_/128, 1), 256, 0, stream>>>(xb, Wvb, qkvb, 1024, 1, 896);

  k_vmix_norm_rope<<<dim3(M_, 8), 128, 0, stream>>>(qkvb, v1, lamb, cosT, sinT,
                                                    qn, kn, vn);
  k_transpose_v<<<dim3(T_/64, B_), 256, 0, stream>>>(vn, vnt);

  k_attn_mfma<<<B_*H_*(T_/128), 256, 0, stream>>>(qn, kn, vnt, x, Wg, yb);

  k_gemm_bf16<<<dim3(M_/128, 6), 256, 0, stream>>>(yb, Wob, out, 768, 0, 0);

  hipMemcpyAsync(out + (size_t)M_*E_, v1, (size_t)M_*D_*sizeof(float),
                 hipMemcpyDeviceToDevice, stream);
}